// Round 1
// 834.866 us; speedup vs baseline: 1.0287x; 1.0287x over previous
//
#include <hip/hip_runtime.h>
#include <hip/hip_bf16.h>

// Problem dims
#define Bb 4
#define Tt 256
#define Ss 128
#define Ff 256
#define Hh 512
#define Vv 1024

typedef __attribute__((ext_vector_type(8))) short bf16x8;   // 8 bf16 = 4 VGPRs
typedef __attribute__((ext_vector_type(4))) float f32x4;    // MFMA accumulator

// ---------------------------------------------------------------------------
// Kernel 1: hs[bt][h] = src[bt,:] @ W1[:F,:] + b1   (1024 x 512)
//           ht[bs][h] = tgt[bs,:] @ W1[F:,:]        ( 512 x 512)
// 8 rows per block, 256 threads; thread owns cols {t, t+256} of 8 rows.
// ---------------------------------------------------------------------------
__global__ __launch_bounds__(256) void precompute_kernel(
    const float* __restrict__ src, const float* __restrict__ tgt,
    const float* __restrict__ W1, const float* __restrict__ b1,
    float* __restrict__ hs, float* __restrict__ ht)
{
    __shared__ float rows[8][Ff];
    const int blk = blockIdx.x;
    const bool is_hs = blk < (Bb * Tt / 8);                // 128 hs blocks, 64 ht blocks
    const int row0 = is_hs ? blk * 8 : (blk - Bb * Tt / 8) * 8;
    const float* in = (is_hs ? src : tgt) + row0 * Ff;
    const float* w  = is_hs ? W1 : (W1 + Ff * Hh);
    float* out      = is_hs ? hs : ht;
    const int t = threadIdx.x;

    for (int i = t; i < 8 * Ff; i += 256) rows[i >> 8][i & (Ff - 1)] = in[i];
    __syncthreads();

    float acc0[8], acc1[8];
#pragma unroll
    for (int r = 0; r < 8; r++) { acc0[r] = 0.f; acc1[r] = 0.f; }

    for (int k = 0; k < Ff; k++) {
        const float w0 = w[k * Hh + t];
        const float w1 = w[k * Hh + t + 256];
#pragma unroll
        for (int r = 0; r < 8; r++) {
            const float x = rows[r][k];
            acc0[r] = fmaf(x, w0, acc0[r]);
            acc1[r] = fmaf(x, w1, acc1[r]);
        }
    }
    const float bias0 = is_hs ? b1[t]       : 0.f;
    const float bias1 = is_hs ? b1[t + 256] : 0.f;
#pragma unroll
    for (int r = 0; r < 8; r++) {
        out[(row0 + r) * Hh + t]       = acc0[r] + bias0;
        out[(row0 + r) * Hh + t + 256] = acc1[r] + bias1;
    }
}

// ---------------------------------------------------------------------------
// Kernel 2: W2T[v][h] = bf16(W2[h][v])   (transpose + cvt, 1 MiB out)
// ---------------------------------------------------------------------------
__global__ __launch_bounds__(256) void w2t_kernel(
    const float* __restrict__ W2, __hip_bfloat16* __restrict__ W2T)
{
    const int idx = blockIdx.x * 256 + threadIdx.x;        // over V*H
    const int v = idx >> 9;                                // / Hh
    const int h = idx & (Hh - 1);
    W2T[idx] = __float2bfloat16(W2[h * Vv + v]);
}

// ---------------------------------------------------------------------------
// Kernel 3 (main): per block = 64 rows (one bt, s0 in {0,64}) x all 1024 cols.
// 512 threads = 8 waves; wave w owns cols [128w, 128w+128), rows 0..63.
//
// v2 structure: the WHOLE A panel (64 x 512 bf16, relu(hs+ht)) is staged into
// LDS once (it's only 64 KB), one __syncthreads, then the 16 K-steps run with
// NO barriers: the 2 waves/SIMD drift and overlap (MFMA pipe vs VMEM/LDS),
// and W2T fragment loads (L2-hot) pipeline freely.
// Rows padded to 520 bf16 (1040 B) so the afrag ds_read_b128 is the minimal
// 8-phase access instead of 16-phase.
// Epilogue: fused log_softmax over V, nontemporal f32 stores (output is
// write-once; keep W2T resident in L2).
// ---------------------------------------------------------------------------
#define APAD 520   // 512 + 8 bf16 pad -> 1040 B row stride (16B aligned)

__global__ __launch_bounds__(512, 2) void joint_main_kernel(
    const float* __restrict__ hs, const float* __restrict__ ht,
    const __hip_bfloat16* __restrict__ W2T, const float* __restrict__ b2,
    float* __restrict__ out)
{
    __shared__ __hip_bfloat16 Abuf[64][APAD];    // ~65 KiB
    __shared__ float redmax[64][8];
    __shared__ float redsum[64][8];

    const int blk  = blockIdx.x;          // 0..2047
    const int bt   = blk >> 1;            // 0..1023
    const int s0   = (blk & 1) * 64;
    const int b    = bt >> 8;             // bt / Tt
    const int tid  = threadIdx.x;
    const int w    = tid >> 6;            // wave 0..7
    const int lane = tid & 63;
    const int quad = lane >> 4;
    const int l15  = lane & 15;

    const float* hsrow  = hs + bt * Hh;
    const float* htbase = ht + (b * Ss + s0) * Hh;

    // B fragment base: lane holds B[k = quad*8+j][n = w*128 + ct*16 + l15]
    // W2T is [v][h] so the 8 k's are 16 contiguous bytes.
    const __hip_bfloat16* bbase = W2T + (w * 128 + l15) * Hh + quad * 8;

    bf16x8 bfrag[2][8];
#define LOAD_B(ki, buf) do {                                               \
        _Pragma("unroll")                                                  \
        for (int ct = 0; ct < 8; ct++)                                     \
            bfrag[buf][ct] =                                               \
                *(const bf16x8*)(bbase + ct * 16 * Hh + (ki) * 32);        \
    } while (0)

    // Issue the first B fragments before staging (independent of LDS).
    LOAD_B(0, 0);

    // ---- Stage the ENTIRE A panel: 64 rows x 512 k, bf16, once. ----------
    // One wave covers one full row per iteration: lane l -> floats [8l,8l+8)
    // (32 B/lane, fully coalesced), 8 iterations over 512 threads.
#pragma unroll
    for (int it = 0; it < 8; ++it) {
        const int idx = it * 512 + tid;        // 0..4095
        const int r   = idx >> 6;              // row 0..63
        const int c   = (idx & 63) * 8;        // col 0..504
        const float* hp = hsrow + c;
        const float* tp = htbase + r * Hh + c;
        const float4 a0 = *(const float4*)(hp);
        const float4 a1 = *(const float4*)(hp + 4);
        const float4 b0 = *(const float4*)(tp);
        const float4 b1 = *(const float4*)(tp + 4);
        union { __hip_bfloat16 h[8]; bf16x8 v; } pk;
        pk.h[0] = __float2bfloat16(fmaxf(a0.x + b0.x, 0.f));
        pk.h[1] = __float2bfloat16(fmaxf(a0.y + b0.y, 0.f));
        pk.h[2] = __float2bfloat16(fmaxf(a0.z + b0.z, 0.f));
        pk.h[3] = __float2bfloat16(fmaxf(a0.w + b0.w, 0.f));
        pk.h[4] = __float2bfloat16(fmaxf(a1.x + b1.x, 0.f));
        pk.h[5] = __float2bfloat16(fmaxf(a1.y + b1.y, 0.f));
        pk.h[6] = __float2bfloat16(fmaxf(a1.z + b1.z, 0.f));
        pk.h[7] = __float2bfloat16(fmaxf(a1.w + b1.w, 0.f));
        *(bf16x8*)&Abuf[r][c] = pk.v;          // 16B ds_write, conflict-free
    }
    __syncthreads();   // the ONLY pre-epilogue barrier

    f32x4 acc[4][8];
#pragma unroll
    for (int rt = 0; rt < 4; rt++)
#pragma unroll
        for (int ct = 0; ct < 8; ct++) {
            f32x4 z = {0.f, 0.f, 0.f, 0.f};
            acc[rt][ct] = z;
        }

    // ---- Barrier-free K loop ---------------------------------------------
#pragma unroll
    for (int ki = 0; ki < 16; ki++) {
        const int cur = ki & 1;
        bf16x8 afrag[4];
#pragma unroll
        for (int rt = 0; rt < 4; rt++)
            afrag[rt] = *(const bf16x8*)&Abuf[rt * 16 + l15][ki * 32 + quad * 8];
        if (ki < 15) LOAD_B(ki + 1, cur ^ 1);
#pragma unroll
        for (int rt = 0; rt < 4; rt++)
#pragma unroll
            for (int ct = 0; ct < 8; ct++)
                acc[rt][ct] = __builtin_amdgcn_mfma_f32_16x16x32_bf16(
                    afrag[rt], bfrag[cur][ct], acc[rt][ct], 0, 0, 0);
    }
#undef LOAD_B

    // ---------------- epilogue: + b2, fused log_softmax over V -------------
    float b2v[8];
#pragma unroll
    for (int ct = 0; ct < 8; ct++) b2v[ct] = b2[w * 128 + ct * 16 + l15];
#pragma unroll
    for (int rt = 0; rt < 4; rt++)
#pragma unroll
        for (int ct = 0; ct < 8; ct++) {
            acc[rt][ct].x += b2v[ct]; acc[rt][ct].y += b2v[ct];
            acc[rt][ct].z += b2v[ct]; acc[rt][ct].w += b2v[ct];
        }

    // lane-local max over its 8 col-tiles, rows = rt*16 + quad*4 + r
    float mrow[4][4];
#pragma unroll
    for (int rt = 0; rt < 4; rt++)
#pragma unroll
        for (int r = 0; r < 4; r++) {
            float m = acc[rt][0][r];
#pragma unroll
            for (int ct = 1; ct < 8; ct++) m = fmaxf(m, acc[rt][ct][r]);
            mrow[rt][r] = m;
        }
    // reduce across the 16 lanes holding the same rows (xor in bits 0..3)
#pragma unroll
    for (int off = 8; off >= 1; off >>= 1)
#pragma unroll
        for (int rt = 0; rt < 4; rt++)
#pragma unroll
            for (int r = 0; r < 4; r++)
                mrow[rt][r] = fmaxf(mrow[rt][r], __shfl_xor(mrow[rt][r], off, 64));

    if (l15 == 0) {
#pragma unroll
        for (int rt = 0; rt < 4; rt++)
#pragma unroll
            for (int r = 0; r < 4; r++)
                redmax[rt * 16 + quad * 4 + r][w] = mrow[rt][r];
    }
    __syncthreads();

    float gmax[4][4];
#pragma unroll
    for (int rt = 0; rt < 4; rt++)
#pragma unroll
        for (int r = 0; r < 4; r++) {
            const int row = rt * 16 + quad * 4 + r;
            float m = redmax[row][0];
#pragma unroll
            for (int wv = 1; wv < 8; wv++) m = fmaxf(m, redmax[row][wv]);
            gmax[rt][r] = m;
        }

    float srow[4][4];
#pragma unroll
    for (int rt = 0; rt < 4; rt++)
#pragma unroll
        for (int r = 0; r < 4; r++) {
            float s = 0.f;
#pragma unroll
            for (int ct = 0; ct < 8; ct++)
                s += __expf(acc[rt][ct][r] - gmax[rt][r]);
            srow[rt][r] = s;
        }
#pragma unroll
    for (int off = 8; off >= 1; off >>= 1)
#pragma unroll
        for (int rt = 0; rt < 4; rt++)
#pragma unroll
            for (int r = 0; r < 4; r++)
                srow[rt][r] += __shfl_xor(srow[rt][r], off, 64);

    if (l15 == 0) {
#pragma unroll
        for (int rt = 0; rt < 4; rt++)
#pragma unroll
            for (int r = 0; r < 4; r++)
                redsum[rt * 16 + quad * 4 + r][w] = srow[rt][r];
    }
    __syncthreads();

#pragma unroll
    for (int rt = 0; rt < 4; rt++)
#pragma unroll
        for (int r = 0; r < 4; r++) {
            const int row = rt * 16 + quad * 4 + r;
            float s = redsum[row][0];
#pragma unroll
            for (int wv = 1; wv < 8; wv++) s += redsum[row][wv];
            const float lse = gmax[rt][r] + __logf(s);
            const int mg = bt * Ss + s0 + row;                  // global row
            float* orow = out + (size_t)mg * Vv + w * 128 + l15;
#pragma unroll
            for (int ct = 0; ct < 8; ct++)
                __builtin_nontemporal_store(acc[rt][ct][r] - lse, &orow[ct * 16]);
        }
}

// ---------------------------------------------------------------------------
extern "C" void kernel_launch(void* const* d_in, const int* in_sizes, int n_in,
                              void* d_out, int out_size, void* d_ws, size_t ws_size,
                              hipStream_t stream)
{
    const float* src = (const float*)d_in[0];   // [B,T,F]
    const float* tgt = (const float*)d_in[1];   // [B,S,F]
    const float* W1  = (const float*)d_in[2];   // [2F,H]
    const float* b1  = (const float*)d_in[3];   // [H]
    const float* W2  = (const float*)d_in[4];   // [H,V]
    const float* b2  = (const float*)d_in[5];   // [V]
    float* outp = (float*)d_out;                // [B,T,S,V]

    char* ws = (char*)d_ws;
    float* hs = (float*)ws;                                              // 2 MiB
    float* ht = (float*)(ws + (size_t)(Bb * Tt * Hh) * 4);               // 1 MiB
    __hip_bfloat16* W2T =
        (__hip_bfloat16*)(ws + (size_t)(Bb * Tt * Hh + Bb * Ss * Hh) * 4); // 1 MiB

    hipLaunchKernelGGL(precompute_kernel, dim3((Bb * Tt + Bb * Ss) / 8), dim3(256),
                       0, stream, src, tgt, W1, b1, hs, ht);
    hipLaunchKernelGGL(w2t_kernel, dim3(Vv * Hh / 256), dim3(256),
                       0, stream, W2, W2T);
    hipLaunchKernelGGL(joint_main_kernel, dim3(Bb * Tt * Ss / 64), dim3(512),
                       0, stream, hs, ht, W2T, b2, outp);
}